// Round 8
// baseline (209.506 us; speedup 1.0000x reference)
//
#include <hip/hip_runtime.h>

// VectorQuantizer R17: TWO kernels. Fused z-pass: transpose+split -> LDS
// frag-order (no zf round-trip), barrier-free full-K MFMA loop, fused
// argmax + gather + zq write. Non-temporal z reads / zq writes keep the
// shared codebook planes (1 MB) resident in each XCD L2 (R16's failure).
//   wh = f16(16*w_hat), wl = f16(16*w_hat - wh)   (uniform x16: argmax-invariant)
//   zh = f16(4*z),      zl = f16(4*z - zh)        (uniform x4:  argmax-invariant)
//   dot = hh + hl + lh  (single f32 accumulator chain; ll ~2^-22 rel, dropped)
// argmin_k ||z_hat - w_hat_k|| == argmax_k <z, w_hat_k>  -> only codebook normalized.
//
// R16 post-mortem: FETCH 175 MB = B re-fetched ~140x from HBM (A-streams +
// zq writes evicted it); B miss latency on the K-loop critical path ->
// MfmaUtil 16.5%. R9-vs-R13 showed in-kernel split is free (hidden in
// stalls) -> the zf round-trip (25us + 64 MB) was waste. R17 deletes it.

typedef _Float16 half8 __attribute__((ext_vector_type(8)));
typedef float    floatx4 __attribute__((ext_vector_type(4)));

#define C_DIM 256
#define K_CODES 1024
#define HW 1024
#define NPIX 32768

// ---------------- kernel 1: normalize codebook + frag-order f16 split -------
// grid 1024 x 256 thr. Unchanged math (verified R0-R16). wfh/wfl emitted in
// MFMA fragment order: plane[(c/64 * 8 + kt)*2048 + ((c/16)&3)*512 + l*8 + j]
// with l = ((t>>3)&3)*16 + (c&15), kt = t>>5, j = t&7  (k = t).
__global__ __launch_bounds__(256) void vq_norm(
        const float* __restrict__ w, float* __restrict__ w_n,
        _Float16* __restrict__ wfh, _Float16* __restrict__ wfl) {
    __shared__ float wsum[4];
    const int t = threadIdx.x;
    const int c = blockIdx.x;
    float x = w[c * C_DIM + t];
    float s = x * x;
    #pragma unroll
    for (int off = 32; off > 0; off >>= 1) s += __shfl_down(s, off, 64);
    if ((t & 63) == 0) wsum[t >> 6] = s;
    __syncthreads();
    float tot = wsum[0] + wsum[1] + wsum[2] + wsum[3];
    float inv = 1.0f / fmaxf(sqrtf(tot), 1e-12f);
    float y = x * inv;
    w_n[c * C_DIM + t] = y;            // row-major: epilogue reads rows coalesced
    float ys = 16.0f * y;
    _Float16 hi = (_Float16)ys;
    _Float16 lo = (_Float16)(ys - (float)hi);
    const int kt = t >> 5, l = ((t >> 3) & 3) * 16 + (c & 15), j = t & 7;
    const size_t fo = ((size_t)(c >> 6) * 8 + kt) * 2048 + ((c >> 4) & 3) * 512
                    + l * 8 + j;
    wfh[fo] = hi;
    wfl[fo] = lo;
}

// ---------------- kernel 2: fused split + full-K GEMM + argmax + zq ---------
// grid 512 (64 px each) x 512 thr (8 waves), 1 block/CU (139.8 KB LDS).
// Phase 1: NT-read z [16c x 64p] slabs, split, transpose via LDS (pk).
// Phase 2: frag-order emit into LDS Ah/Al (64 KB).
// Phase 3: barrier-free K-loop; wave w covers code group p*8+w (64 codes),
//          2 passes; per kt: 8 B-loads (L2-hot), 8 A ds_reads, 48 MFMA.
// Phase 4: argmax over 16 parked entries; gather w_n rows; NT zq stores.
__global__ __launch_bounds__(512, 1) void vq_fused(
        const float* __restrict__ z,
        const _Float16* __restrict__ wfh, const _Float16* __restrict__ wfl,
        const float* __restrict__ w_n,
        float* __restrict__ zq, float* __restrict__ idx_out) {
    __shared__ float tile[64][257];          // 65.8 KB: pk (phase 1/2) then gather tile
    __shared__ _Float16 Ahl[2][16384];       // 64 KB: Ah, Al (frag order)
    __shared__ float red_v[64][16];          // 4 KB
    __shared__ int   red_i[64][16];          // 4 KB
    __shared__ int   idx_s[64];
    unsigned (*pk)[257] = (unsigned (*)[257])tile;   // h | l<<16
    _Float16* Ah = Ahl[0];
    _Float16* Al = Ahl[1];

    const int tid  = threadIdx.x;            // 0..511
    const int lane = tid & 63, wave = tid >> 6;   // wave 0..7
    const int quad = lane >> 4, l15 = lane & 15;
    const int g4   = blockIdx.x;             // 64-pixel group 0..511
    const int pg = g4 * 64, b = pg >> 10, p0 = pg & 1023;

    // ---- phase 1: z read (NT) + split + transpose into pk ------------------
    {
        const float* zp = z + (size_t)b * (C_DIM * HW) + p0;
        const int cc = tid >> 4, pp = (tid & 15) * 4;    // cc 0..31, pp 0..60
        #pragma unroll
        for (int it = 0; it < 8; it++) {
            const int c = it * 32 + cc;
            floatx4 v = __builtin_nontemporal_load(
                            (const floatx4*)(zp + (size_t)c * HW + pp));
            #pragma unroll
            for (int j = 0; j < 4; j++) {
                float xs = 4.0f * v[j];                 // same split path as R9-R16
                _Float16 h = (_Float16)xs;              // bitwise-identical operands
                _Float16 l = (_Float16)(xs - (float)h);
                pk[pp + j][c] = (unsigned)__builtin_bit_cast(unsigned short, h)
                              | ((unsigned)__builtin_bit_cast(unsigned short, l) << 16);
            }
        }
    }
    __syncthreads();

    // ---- phase 2: frag-order emit into LDS Ah/Al ---------------------------
    {
        const int u = (tid >> 6) & 3, kth = tid >> 8;    // u 0..3, kth 0..1
        const int row = u * 16 + (lane & 15);
        #pragma unroll
        for (int i = 0; i < 4; i++) {
            const int kt = kth * 4 + i;
            half8 hv, lv;
            #pragma unroll
            for (int j = 0; j < 8; j++) {
                unsigned v = pk[row][kt * 32 + (lane >> 4) * 8 + j];
                hv[j] = __builtin_bit_cast(_Float16, (unsigned short)(v & 0xffffu));
                lv[j] = __builtin_bit_cast(_Float16, (unsigned short)(v >> 16));
            }
            *(half8*)&Ah[kt * 2048 + u * 512 + lane * 8] = hv;
            *(half8*)&Al[kt * 2048 + u * 512 + lane * 8] = lv;
        }
    }
    __syncthreads();                         // A staged; pk dead

    // ---- phase 3: barrier-free K-loop (2 passes x 8 kt) --------------------
    for (int p = 0; p < 2; p++) {
        const int g4w = p * 8 + wave;        // code group 0..15
        const int cb  = g4w * 64;
        const _Float16* pBh = wfh + (size_t)g4w * 16384 + lane * 8;
        const _Float16* pBl = wfl + (size_t)g4w * 16384 + lane * 8;

        floatx4 acc[4][4];
        #pragma unroll
        for (int i = 0; i < 4; i++)
            #pragma unroll
            for (int j = 0; j < 4; j++) acc[i][j] = (floatx4){0.f, 0.f, 0.f, 0.f};

        for (int kt = 0; kt < 8; kt++) {
            half8 bh[4], bl[4], ah[4], al[4];
            #pragma unroll
            for (int i = 0; i < 4; i++) {
                bh[i] = *(const half8*)(pBh + kt * 2048 + i * 512);
                bl[i] = *(const half8*)(pBl + kt * 2048 + i * 512);
                ah[i] = *(const half8*)&Ah[kt * 2048 + i * 512 + lane * 8];
                al[i] = *(const half8*)&Al[kt * 2048 + i * 512 + lane * 8];
            }
            __builtin_amdgcn_s_setprio(1);
            #pragma unroll
            for (int mi = 0; mi < 4; mi++)
                #pragma unroll
                for (int ni = 0; ni < 4; ni++) {
                    acc[mi][ni] = __builtin_amdgcn_mfma_f32_16x16x32_f16(ah[mi], bh[ni], acc[mi][ni], 0, 0, 0);
                    acc[mi][ni] = __builtin_amdgcn_mfma_f32_16x16x32_f16(ah[mi], bl[ni], acc[mi][ni], 0, 0, 0);
                    acc[mi][ni] = __builtin_amdgcn_mfma_f32_16x16x32_f16(al[mi], bh[ni], acc[mi][ni], 0, 0, 0);
                }
            __builtin_amdgcn_s_setprio(0);
        }

        // fold this pass's 64 codes into per-row best, park in LDS
        #pragma unroll
        for (int mi = 0; mi < 4; mi++) {
            #pragma unroll
            for (int r = 0; r < 4; r++) {
                float bv = -__builtin_inff();
                int   bi = 0x7fffffff;
                #pragma unroll
                for (int ni = 0; ni < 4; ni++) {
                    float v = acc[mi][ni][r];
                    int  ci = cb + ni * 16 + l15;
                    if (v > bv || (v == bv && ci < bi)) { bv = v; bi = ci; }
                }
                #pragma unroll
                for (int mk = 8; mk; mk >>= 1) {
                    float ov = __shfl_xor(bv, mk, 16);
                    int   oi = __shfl_xor(bi, mk, 16);
                    if (ov > bv || (ov == bv && oi < bi)) { bv = ov; bi = oi; }
                }
                if (l15 == 0) {
                    int row = mi * 16 + quad * 4 + r;   // C/D: row=(lane>>4)*4+reg
                    red_v[row][g4w] = bv;
                    red_i[row][g4w] = bi;
                }
            }
        }
    }
    __syncthreads();                         // all 16 entries parked; Ah/Al dead

    // ---- phase 4a: final argmax (scan code-ascending -> ref tie-break) -----
    if (tid < 64) {
        float bv = red_v[tid][0]; int bi = red_i[tid][0];
        #pragma unroll
        for (int e = 1; e < 16; e++) {
            float v = red_v[tid][e];
            int   c = red_i[tid][e];
            if (v > bv || (v == bv && c < bi)) { bv = v; bi = c; }
        }
        idx_s[tid] = bi;
        idx_out[pg + tid] = (float)bi;
    }
    __syncthreads();

    // ---- phase 4b: gather codebook rows -> tile (overlays dead pk) ---------
    #pragma unroll
    for (int i = 0; i < 8; i++) {
        const int px = wave * 8 + i;
        const int row = idx_s[px];           // wave-uniform broadcast
        floatx4 v = *(const floatx4*)(w_n + (size_t)row * C_DIM + lane * 4);
        *(floatx4*)&tile[px][lane * 4] = v;
    }
    __syncthreads();

    // ---- phase 4c: NT zq stores, float4 along pixels -----------------------
    float* zqb = zq + (size_t)b * (C_DIM * HW) + p0;
    #pragma unroll
    for (int it = 0; it < 8; it++) {
        const int c  = it * 32 + wave * 4 + quad;        // 0..255
        const int px = l15 * 4;
        floatx4 v = { tile[px][c], tile[px + 1][c], tile[px + 2][c], tile[px + 3][c] };
        __builtin_nontemporal_store(v, (floatx4*)(zqb + (size_t)c * HW + px));
    }
}

// ---------------- launcher --------------------------------------------------
extern "C" void kernel_launch(void* const* d_in, const int* in_sizes, int n_in,
                              void* d_out, int out_size, void* d_ws, size_t ws_size,
                              hipStream_t stream) {
    const float* z = (const float*)d_in[0];   // 32*256*32*32
    const float* w = (const float*)d_in[1];   // 1024*256
    float* out     = (float*)d_out;           // z_q (8388608) ++ indices (32768)

    char* ws = (char*)d_ws;                              // 2 MB used
    float*    w_n  = (float*)(ws);                       //  0 .. 1 MB
    _Float16* wfh  = (_Float16*)(ws + (1u << 20));       //  1 .. 1.5 MB
    _Float16* wfl  = (_Float16*)(ws + (1u << 20) + (1u << 19)); // 1.5 .. 2 MB

    vq_norm<<<K_CODES, 256, 0, stream>>>(w, w_n, wfh, wfl);
    vq_fused<<<NPIX / 64, 512, 0, stream>>>(z, wfh, wfl, w_n,
                                            out, out + 8388608);
}